// Round 4
// baseline (186.218 us; speedup 1.0000x reference)
//
#include <hip/hip_runtime.h>

#define F_N 100000
#define V_N 30000
#define DD 15          // domain size D
#define TILE 225       // D*D
#define T_N (2 * F_N)  // 200000 f2v messages
#define NSLOT 256
#define MPB 8          // factors per block in minplus kernel

// ---- workspace layout (float offsets) ----
static const size_t M_OFF     = 0;          // float[T_N*DD] = 3,000,000
static const size_t DIST_OFF  = 3000000;    // float[V_N*DD] = 450,000
static const size_t HEAD_OFF  = 3450048;    // int[V_N]
static const size_t NEXT_OFF  = 3480064;    // int[T_N]
static const size_t AMAX_OFF  = 3680064;    // int[V_N]
static const size_t SLOTP_OFF = 3710080;    // float[256]
static const size_t SLOTC_OFF = 3710336;    // float[256]
static const size_t ENT_OFF   = 3710592;    // float[1]

__global__ void k_init(int* __restrict__ head, float* __restrict__ slots) {
    int i = blockIdx.x * blockDim.x + threadIdx.x;
    if (i < V_N) head[i] = -1;
    if (i < 2 * NSLOT + 1) slots[i] = 0.0f;   // slotP, slotC, ent (contiguous)
}

// Invert scatter via linked lists: head[v] -> chain of t's.
__global__ void k_build(const int* __restrict__ scat,
                        int* __restrict__ head,
                        int* __restrict__ next) {
    int t = blockIdx.x * blockDim.x + threadIdx.x;
    if (t < T_N) {
        int v = scat[t];
        int old = atomicExch(&head[v], t);
        next[t] = old;
    }
}

// Block handles 8 factors: stage cost tiles via float4 (coalesced, single read),
// compute 15 row-mins + 15 col-mins per factor, write m rows (NO atomics).
__global__ __launch_bounds__(256) void k_minplus(
        const float* __restrict__ msgs,
        const float* __restrict__ cost,
        float* __restrict__ m) {
    __shared__ __align__(16) float tile[MPB * TILE];   // 1800 floats
    __shared__ float mlds[2 * MPB * DD];               // 240: [0,120)=rv2f, [120,240)=cv2f
    int f0  = blockIdx.x * MPB;
    int tid = threadIdx.x;

    const float4* src4 = reinterpret_cast<const float4*>(cost + (size_t)f0 * TILE);
    float4* dst4 = reinterpret_cast<float4*>(tile);
    if (tid < 225) {                       // 450 float4 total
        dst4[tid] = src4[tid];
        dst4[tid + 225] = src4[tid + 225];
    }
    if (tid < 2 * MPB * DD) {
        mlds[tid] = (tid < MPB * DD) ? msgs[(size_t)f0 * DD + tid]
                                     : msgs[(size_t)(F_N + f0) * DD + (tid - MPB * DD)];
    }
    __syncthreads();

    int q = tid >> 5;          // factor within block
    int r = tid & 31;          // 0..29 active
    if (r < 30) {
        bool is_row = (r < DD);
        int i = is_row ? r : (r - DD);
        int f = f0 + q;
        // m_f2rv (row-min over j) uses m_cv2f = msgs[F_N+f]; m_f2cv uses m_rv2f = msgs[f]
        const float* mb = is_row ? &mlds[MPB * DD + q * DD] : &mlds[q * DD];
        const float* Cf = &tile[q * TILE];
        float mn = 1e30f;
#pragma unroll
        for (int k = 0; k < DD; ++k) {
            int a = is_row ? (i * DD + k) : (k * DD + i);
            mn = fminf(mn, Cf[a] + mb[k]);
        }
        size_t t = is_row ? (size_t)f : (size_t)(F_N + f);
        m[t * DD + i] = mn;
    }
}

// 16 threads per variable: lane k owns belief[k]. Chain walk shared by the
// group (broadcast next[], contiguous 60B m-row). Softmax/entropy/argmax via
// width-16 shfl_xor butterflies. 480k threads -> 29 waves/CU, latency hidden.
__global__ __launch_bounds__(256) void k_gather_softmax(
        const float* __restrict__ m,
        const int* __restrict__ head,
        const int* __restrict__ next,
        float* __restrict__ dist,
        int*   __restrict__ amax,
        float* __restrict__ ent) {
    int gid = blockIdx.x * 256 + threadIdx.x;
    int v = gid >> 4;
    int k = gid & 15;
    bool act = (v < V_N) && (k < DD);
    float b = 0.0f;
    if (v < V_N) {
        int t = head[v];
        while (t >= 0) {
            if (k < DD) b += m[(size_t)t * DD + k];
            t = next[t];
        }
    }
    // group min of belief
    float bm = act ? b : 1e30f;
#pragma unroll
    for (int off = 1; off < 16; off <<= 1) bm = fminf(bm, __shfl_xor(bm, off, 16));
    float e = act ? expf(bm - b) : 0.0f;
    float den = e;
#pragma unroll
    for (int off = 1; off < 16; off <<= 1) den += __shfl_xor(den, off, 16);
    float dk = e / den;
    float entp = 0.0f;
    if (act) {
        dist[(size_t)v * DD + k] = dk;
        entp = -dk * log2f(dk + 1e-6f);
    }
    // argmax with first-max (lowest index on tie) semantics
    float av = act ? dk : -1.0f;
    int   ai = k;
#pragma unroll
    for (int off = 1; off < 16; off <<= 1) {
        float ov = __shfl_xor(av, off, 16);
        int   oi = __shfl_xor(ai, off, 16);
        if (ov > av || (ov == av && oi < ai)) { av = ov; ai = oi; }
    }
    if (k == 0 && v < V_N) amax[v] = ai;
    // entropy: full-wave reduce, one atomic per wave
#pragma unroll
    for (int off = 32; off > 0; off >>= 1) entp += __shfl_down(entp, off, 64);
    if ((threadIdx.x & 63) == 0) atomicAdd(ent, entp);
}

// One wave per factor: per_f = drv^T C dcv, cost = C[amax,amax].
__global__ __launch_bounds__(256) void k_factor_loss(
        const float* __restrict__ cost,
        const float* __restrict__ dist,
        const int*   __restrict__ amax,
        const int*   __restrict__ rv_idx,
        const int*   __restrict__ cv_idx,
        float* __restrict__ slotP,
        float* __restrict__ slotC) {
    int gtid = blockIdx.x * 256 + threadIdx.x;
    int f    = gtid >> 6;
    int lane = threadIdx.x & 63;
    float s = 0.0f, c = 0.0f;
    if (f < F_N) {
        int rv = rv_idx[f], cv = cv_idx[f];
        const float* dr = dist + (size_t)rv * DD;
        const float* dc = dist + (size_t)cv * DD;
        const float* Cf = cost + (size_t)f * TILE;
#pragma unroll
        for (int t = 0; t < 4; ++t) {
            int e = lane + t * 64;
            if (e < TILE) {
                int i = e / DD;
                int j = e - i * DD;
                s += dr[i] * Cf[e] * dc[j];
            }
        }
        if (lane == 0) c = Cf[amax[rv] * DD + amax[cv]];
    }
#pragma unroll
    for (int off = 32; off > 0; off >>= 1) s += __shfl_down(s, off, 64);
    __shared__ float sP[4], sC[4];
    int w = threadIdx.x >> 6;
    if (lane == 0) { sP[w] = s; sC[w] = c; }
    __syncthreads();
    if (threadIdx.x == 0) {
        float tp = sP[0] + sP[1] + sP[2] + sP[3];
        float tc = sC[0] + sC[1] + sC[2] + sC[3];
        int slot = blockIdx.x & (NSLOT - 1);
        atomicAdd(&slotP[slot], tp);
        atomicAdd(&slotC[slot], tc);
    }
}

__global__ void k_final(const float* __restrict__ slotP,
                        const float* __restrict__ slotC,
                        const float* __restrict__ ent,
                        float* __restrict__ out) {
    int t = threadIdx.x;   // 256 threads
    float p = slotP[t], c = slotC[t];
#pragma unroll
    for (int off = 32; off > 0; off >>= 1) {
        p += __shfl_down(p, off, 64);
        c += __shfl_down(c, off, 64);
    }
    __shared__ float sp[4], sc[4];
    if ((t & 63) == 0) { sp[t >> 6] = p; sc[t >> 6] = c; }
    __syncthreads();
    if (t == 0) {
        out[0] = (sp[0] + sp[1] + sp[2] + sp[3]) + 0.1f * (ent[0] / (float)V_N);
        out[1] = (sc[0] + sc[1] + sc[2] + sc[3]);
    }
}

extern "C" void kernel_launch(void* const* d_in, const int* in_sizes, int n_in,
                              void* d_out, int out_size, void* d_ws, size_t ws_size,
                              hipStream_t stream) {
    const float* msgs = (const float*)d_in[0];   // (4*F_N, 15)
    const float* cost = (const float*)d_in[1];   // (F_N, 15, 15)
    const int* scat   = (const int*)d_in[46];    // f2v_per_v_scatter_idxes (2*F_N)
    const int* rv     = (const int*)d_in[48];    // rv_idxes (F_N)
    const int* cv     = (const int*)d_in[49];    // cv_idxes (F_N)

    float* ws    = (float*)d_ws;
    float* m     = ws + M_OFF;
    float* dist  = ws + DIST_OFF;
    int*   head  = (int*)(ws + HEAD_OFF);
    int*   next  = (int*)(ws + NEXT_OFF);
    int*   amax  = (int*)(ws + AMAX_OFF);
    float* slotP = ws + SLOTP_OFF;
    float* slotC = ws + SLOTC_OFF;
    float* ent   = ws + ENT_OFF;
    float* out   = (float*)d_out;

    k_init<<<(V_N + 255) / 256, 256, 0, stream>>>(head, slotP);
    k_build<<<(T_N + 255) / 256, 256, 0, stream>>>(scat, head, next);
    k_minplus<<<F_N / MPB, 256, 0, stream>>>(msgs, cost, m);
    k_gather_softmax<<<(V_N * 16 + 255) / 256, 256, 0, stream>>>(m, head, next, dist, amax, ent);
    k_factor_loss<<<(F_N * 64 + 255) / 256, 256, 0, stream>>>(cost, dist, amax, rv, cv, slotP, slotC);
    k_final<<<1, 256, 0, stream>>>(slotP, slotC, ent, out);
}

// Round 5
// 186.182 us; speedup vs baseline: 1.0002x; 1.0002x over previous
//
#include <hip/hip_runtime.h>

#define F_N 100000
#define V_N 30000
#define DD 15          // domain size D
#define DP 16          // padded row stride (64 B / cacheline)
#define TILE 225       // D*D
#define T_N (2 * F_N)  // 200000 f2v messages
#define NSLOT 256
#define MPB 8          // factors per block in minplus kernel
#define CAP 32         // bucket capacity per variable

// ---- workspace layout (float offsets) ----
static const size_t M_OFF     = 0;          // float[T_N*DP]  = 3,200,000
static const size_t DIST_OFF  = 3200000;    // float[V_N*DP]  = 480,000
static const size_t CNT_OFF   = 3680000;    // int[V_N]
static const size_t TLIST_OFF = 3710048;    // int[V_N*CAP]   = 960,000
static const size_t AMAX_OFF  = 4670048;    // int[V_N]
static const size_t SLOTP_OFF = 4700064;    // float[256]
static const size_t SLOTC_OFF = 4700320;    // float[256]
static const size_t ENT_OFF   = 4700576;    // float[1]

__global__ void k_init(int* __restrict__ cnt, float* __restrict__ slots) {
    int i = blockIdx.x * blockDim.x + threadIdx.x;
    if (i < V_N) cnt[i] = 0;
    if (i < 2 * NSLOT + 1) slots[i] = 0.0f;   // slotP, slotC, ent (contiguous)
}

// Bucket-place: invert the scatter with one int atomic per message.
__global__ void k_place(const int* __restrict__ scat,
                        int* __restrict__ cnt,
                        int* __restrict__ tlist) {
    int t = blockIdx.x * blockDim.x + threadIdx.x;
    if (t < T_N) {
        int v = scat[t];
        int pos = atomicAdd(&cnt[v], 1);
        if (pos < CAP) tlist[v * CAP + pos] = t;
    }
}

// Block handles 8 factors: stage cost tiles via float4 (coalesced, single read),
// compute 15 row-mins + 15 col-mins per factor, write padded m rows (NO atomics).
__global__ __launch_bounds__(256) void k_minplus(
        const float* __restrict__ msgs,
        const float* __restrict__ cost,
        float* __restrict__ m) {
    __shared__ __align__(16) float tile[MPB * TILE];   // 1800 floats
    __shared__ float mlds[2 * MPB * DD];               // 240: [0,120)=rv2f, [120,240)=cv2f
    int f0  = blockIdx.x * MPB;
    int tid = threadIdx.x;

    const float4* src4 = reinterpret_cast<const float4*>(cost + (size_t)f0 * TILE);
    float4* dst4 = reinterpret_cast<float4*>(tile);
    if (tid < 225) {                       // 450 float4 total
        dst4[tid] = src4[tid];
        dst4[tid + 225] = src4[tid + 225];
    }
    if (tid < 2 * MPB * DD) {
        mlds[tid] = (tid < MPB * DD) ? msgs[(size_t)f0 * DD + tid]
                                     : msgs[(size_t)(F_N + f0) * DD + (tid - MPB * DD)];
    }
    __syncthreads();

    int q = tid >> 5;          // factor within block
    int r = tid & 31;          // 0..29 active
    if (r < 30) {
        bool is_row = (r < DD);
        int i = is_row ? r : (r - DD);
        int f = f0 + q;
        // m_f2rv (row-min over j) uses m_cv2f = msgs[F_N+f]; m_f2cv uses m_rv2f = msgs[f]
        const float* mb = is_row ? &mlds[MPB * DD + q * DD] : &mlds[q * DD];
        const float* Cf = &tile[q * TILE];
        float mn = 1e30f;
#pragma unroll
        for (int k = 0; k < DD; ++k) {
            int a = is_row ? (i * DD + k) : (k * DD + i);
            mn = fminf(mn, Cf[a] + mb[k]);
        }
        size_t t = is_row ? (size_t)f : (size_t)(F_N + f);
        m[t * DP + i] = mn;
    }
}

// 16 lanes per variable: lane k owns belief[k]. Bucket indices prefetched
// (coalesced) and broadcast via shfl; m-row loads independent (2-way MLP).
// Softmax/entropy/argmax via width-16 shfl_xor butterflies.
__global__ __launch_bounds__(256) void k_gather_softmax(
        const float* __restrict__ m,
        const int* __restrict__ cnt,
        const int* __restrict__ tlist,
        float* __restrict__ dist,
        int*   __restrict__ amax,
        float* __restrict__ ent) {
    int gid = blockIdx.x * 256 + threadIdx.x;
    int v = gid >> 4;
    int k = gid & 15;
    bool act = (v < V_N) && (k < DD);
    float b0 = 0.0f, b1 = 0.0f;
    if (v < V_N) {
        int n = cnt[v];
        if (n > CAP) n = CAP;
        int n1 = (n < 16) ? n : 16;
        int tl  = (k < n)       ? tlist[v * CAP + k]      : 0;
        int tl2 = (k + 16 < n)  ? tlist[v * CAP + k + 16] : 0;
        int i = 0;
        for (; i + 1 < n1; i += 2) {
            int ta = __shfl(tl, i, 16);
            int tb = __shfl(tl, i + 1, 16);
            if (k < DD) {
                b0 += m[(size_t)ta * DP + k];
                b1 += m[(size_t)tb * DP + k];
            }
        }
        if (i < n1) {
            int ta = __shfl(tl, i, 16);
            if (k < DD) b0 += m[(size_t)ta * DP + k];
        }
        for (int j = 16; j < n; ++j) {          // rare: deg > 16
            int ta = __shfl(tl2, j - 16, 16);
            if (k < DD) b1 += m[(size_t)ta * DP + k];
        }
    }
    float b = b0 + b1;
    // group min of belief
    float bm = act ? b : 1e30f;
#pragma unroll
    for (int off = 1; off < 16; off <<= 1) bm = fminf(bm, __shfl_xor(bm, off, 16));
    float e = act ? expf(bm - b) : 0.0f;
    float den = e;
#pragma unroll
    for (int off = 1; off < 16; off <<= 1) den += __shfl_xor(den, off, 16);
    float dk = e / den;
    float entp = 0.0f;
    if (act) {
        dist[(size_t)v * DP + k] = dk;
        entp = -dk * log2f(dk + 1e-6f);
    }
    // argmax with first-max (lowest index on tie) semantics
    float av = act ? dk : -1.0f;
    int   ai = k;
#pragma unroll
    for (int off = 1; off < 16; off <<= 1) {
        float ov = __shfl_xor(av, off, 16);
        int   oi = __shfl_xor(ai, off, 16);
        if (ov > av || (ov == av && oi < ai)) { av = ov; ai = oi; }
    }
    if (k == 0 && v < V_N) amax[v] = ai;
    // entropy: full-wave reduce, one atomic per wave
#pragma unroll
    for (int off = 32; off > 0; off >>= 1) entp += __shfl_down(entp, off, 64);
    if ((threadIdx.x & 63) == 0) atomicAdd(ent, entp);
}

// One wave per factor: per_f = drv^T C dcv, cost = C[amax,amax].
__global__ __launch_bounds__(256) void k_factor_loss(
        const float* __restrict__ cost,
        const float* __restrict__ dist,
        const int*   __restrict__ amax,
        const int*   __restrict__ rv_idx,
        const int*   __restrict__ cv_idx,
        float* __restrict__ slotP,
        float* __restrict__ slotC) {
    int gtid = blockIdx.x * 256 + threadIdx.x;
    int f    = gtid >> 6;
    int lane = threadIdx.x & 63;
    float s = 0.0f, c = 0.0f;
    if (f < F_N) {
        int rv = rv_idx[f], cv = cv_idx[f];
        const float* dr = dist + (size_t)rv * DP;
        const float* dc = dist + (size_t)cv * DP;
        const float* Cf = cost + (size_t)f * TILE;
#pragma unroll
        for (int t = 0; t < 4; ++t) {
            int e = lane + t * 64;
            if (e < TILE) {
                int i = e / DD;
                int j = e - i * DD;
                s += dr[i] * Cf[e] * dc[j];
            }
        }
        if (lane == 0) c = Cf[amax[rv] * DD + amax[cv]];
    }
#pragma unroll
    for (int off = 32; off > 0; off >>= 1) s += __shfl_down(s, off, 64);
    __shared__ float sP[4], sC[4];
    int w = threadIdx.x >> 6;
    if (lane == 0) { sP[w] = s; sC[w] = c; }
    __syncthreads();
    if (threadIdx.x == 0) {
        float tp = sP[0] + sP[1] + sP[2] + sP[3];
        float tc = sC[0] + sC[1] + sC[2] + sC[3];
        int slot = blockIdx.x & (NSLOT - 1);
        atomicAdd(&slotP[slot], tp);
        atomicAdd(&slotC[slot], tc);
    }
}

__global__ void k_final(const float* __restrict__ slotP,
                        const float* __restrict__ slotC,
                        const float* __restrict__ ent,
                        float* __restrict__ out) {
    int t = threadIdx.x;   // 256 threads
    float p = slotP[t], c = slotC[t];
#pragma unroll
    for (int off = 32; off > 0; off >>= 1) {
        p += __shfl_down(p, off, 64);
        c += __shfl_down(c, off, 64);
    }
    __shared__ float sp[4], sc[4];
    if ((t & 63) == 0) { sp[t >> 6] = p; sc[t >> 6] = c; }
    __syncthreads();
    if (t == 0) {
        out[0] = (sp[0] + sp[1] + sp[2] + sp[3]) + 0.1f * (ent[0] / (float)V_N);
        out[1] = (sc[0] + sc[1] + sc[2] + sc[3]);
    }
}

extern "C" void kernel_launch(void* const* d_in, const int* in_sizes, int n_in,
                              void* d_out, int out_size, void* d_ws, size_t ws_size,
                              hipStream_t stream) {
    const float* msgs = (const float*)d_in[0];   // (4*F_N, 15)
    const float* cost = (const float*)d_in[1];   // (F_N, 15, 15)
    const int* scat   = (const int*)d_in[46];    // f2v_per_v_scatter_idxes (2*F_N)
    const int* rv     = (const int*)d_in[48];    // rv_idxes (F_N)
    const int* cv     = (const int*)d_in[49];    // cv_idxes (F_N)

    float* ws    = (float*)d_ws;
    float* m     = ws + M_OFF;
    float* dist  = ws + DIST_OFF;
    int*   cnt   = (int*)(ws + CNT_OFF);
    int*   tlist = (int*)(ws + TLIST_OFF);
    int*   amax  = (int*)(ws + AMAX_OFF);
    float* slotP = ws + SLOTP_OFF;
    float* slotC = ws + SLOTC_OFF;
    float* ent   = ws + ENT_OFF;
    float* out   = (float*)d_out;

    k_init<<<(V_N + 255) / 256, 256, 0, stream>>>(cnt, slotP);
    k_place<<<(T_N + 255) / 256, 256, 0, stream>>>(scat, cnt, tlist);
    k_minplus<<<F_N / MPB, 256, 0, stream>>>(msgs, cost, m);
    k_gather_softmax<<<(V_N * 16 + 255) / 256, 256, 0, stream>>>(m, cnt, tlist, dist, amax, ent);
    k_factor_loss<<<(F_N * 64 + 255) / 256, 256, 0, stream>>>(cost, dist, amax, rv, cv, slotP, slotC);
    k_final<<<1, 256, 0, stream>>>(slotP, slotC, ent, out);
}

// Round 6
// 94.975 us; speedup vs baseline: 1.9607x; 1.9603x over previous
//
#include <hip/hip_runtime.h>

#define F_N 100000
#define V_N 30000
#define DD 15          // domain size D
#define DP 16          // padded row stride (64 B / cacheline)
#define TILE 225       // D*D
#define T_N (2 * F_N)  // 200000 f2v messages
#define NSLOT 256
#define MPB 8          // factors per block in minplus kernel
#define CAP 32         // bucket capacity per variable

// ---- workspace layout (float offsets) ----
static const size_t M_OFF     = 0;          // float[T_N*DP]  = 3,200,000
static const size_t DIST_OFF  = 3200000;    // float[V_N*DP]  = 480,000
static const size_t CNT_OFF   = 3680000;    // int[V_N]
static const size_t TLIST_OFF = 3710048;    // int[V_N*CAP]   = 960,000
static const size_t AMAX_OFF  = 4670048;    // int[V_N]
static const size_t SLOTP_OFF = 4700064;    // float[NSLOT]
static const size_t SLOTC_OFF = 4700320;    // float[NSLOT]
static const size_t SLOTE_OFF = 4700576;    // float[NSLOT]

__global__ void k_init(int* __restrict__ cnt, float* __restrict__ slots) {
    int i = blockIdx.x * blockDim.x + threadIdx.x;
    if (i < V_N) cnt[i] = 0;
    if (i < 3 * NSLOT) slots[i] = 0.0f;   // slotP, slotC, slotE (contiguous)
}

// Bucket-place: invert the scatter with one int atomic per message
// (distributed over 30k counter addresses -> no serialization hotspot).
__global__ void k_place(const int* __restrict__ scat,
                        int* __restrict__ cnt,
                        int* __restrict__ tlist) {
    int t = blockIdx.x * blockDim.x + threadIdx.x;
    if (t < T_N) {
        int v = scat[t];
        int pos = atomicAdd(&cnt[v], 1);
        if (pos < CAP) tlist[v * CAP + pos] = t;
    }
}

// Block handles 8 factors: stage cost tiles via float4 (coalesced, single read),
// compute 15 row-mins + 15 col-mins per factor, write padded m rows (NO atomics).
__global__ __launch_bounds__(256) void k_minplus(
        const float* __restrict__ msgs,
        const float* __restrict__ cost,
        float* __restrict__ m) {
    __shared__ __align__(16) float tile[MPB * TILE];   // 1800 floats
    __shared__ float mlds[2 * MPB * DD];               // 240: [0,120)=rv2f, [120,240)=cv2f
    int f0  = blockIdx.x * MPB;
    int tid = threadIdx.x;

    const float4* src4 = reinterpret_cast<const float4*>(cost + (size_t)f0 * TILE);
    float4* dst4 = reinterpret_cast<float4*>(tile);
    if (tid < 225) {                       // 450 float4 total
        dst4[tid] = src4[tid];
        dst4[tid + 225] = src4[tid + 225];
    }
    if (tid < 2 * MPB * DD) {
        mlds[tid] = (tid < MPB * DD) ? msgs[(size_t)f0 * DD + tid]
                                     : msgs[(size_t)(F_N + f0) * DD + (tid - MPB * DD)];
    }
    __syncthreads();

    int q = tid >> 5;          // factor within block
    int r = tid & 31;          // 0..29 active
    if (r < 30) {
        bool is_row = (r < DD);
        int i = is_row ? r : (r - DD);
        int f = f0 + q;
        // m_f2rv (row-min over j) uses m_cv2f = msgs[F_N+f]; m_f2cv uses m_rv2f = msgs[f]
        const float* mb = is_row ? &mlds[MPB * DD + q * DD] : &mlds[q * DD];
        const float* Cf = &tile[q * TILE];
        float mn = 1e30f;
#pragma unroll
        for (int k = 0; k < DD; ++k) {
            int a = is_row ? (i * DD + k) : (k * DD + i);
            mn = fminf(mn, Cf[a] + mb[k]);
        }
        size_t t = is_row ? (size_t)f : (size_t)(F_N + f);
        m[t * DP + i] = mn;
    }
}

// 16 lanes per variable: lane k owns belief[k]. Bucket indices prefetched
// (coalesced) and broadcast via shfl; m-row loads independent.
// Softmax/entropy/argmax via width-16 shfl_xor butterflies.
// Entropy: wave reduce -> LDS -> ONE atomic per block into 256 spread slots.
__global__ __launch_bounds__(256) void k_gather_softmax(
        const float* __restrict__ m,
        const int* __restrict__ cnt,
        const int* __restrict__ tlist,
        float* __restrict__ dist,
        int*   __restrict__ amax,
        float* __restrict__ slotE) {
    int gid = blockIdx.x * 256 + threadIdx.x;
    int v = gid >> 4;
    int k = gid & 15;
    bool act = (v < V_N) && (k < DD);
    float b0 = 0.0f, b1 = 0.0f;
    if (v < V_N) {
        int n = cnt[v];
        if (n > CAP) n = CAP;
        int n1 = (n < 16) ? n : 16;
        int tl  = (k < n)       ? tlist[v * CAP + k]      : 0;
        int tl2 = (k + 16 < n)  ? tlist[v * CAP + k + 16] : 0;
        int i = 0;
        for (; i + 1 < n1; i += 2) {
            int ta = __shfl(tl, i, 16);
            int tb = __shfl(tl, i + 1, 16);
            if (k < DD) {
                b0 += m[(size_t)ta * DP + k];
                b1 += m[(size_t)tb * DP + k];
            }
        }
        if (i < n1) {
            int ta = __shfl(tl, i, 16);
            if (k < DD) b0 += m[(size_t)ta * DP + k];
        }
        for (int j = 16; j < n; ++j) {          // rare: deg > 16
            int ta = __shfl(tl2, j - 16, 16);
            if (k < DD) b1 += m[(size_t)ta * DP + k];
        }
    }
    float b = b0 + b1;
    // group min of belief
    float bm = act ? b : 1e30f;
#pragma unroll
    for (int off = 1; off < 16; off <<= 1) bm = fminf(bm, __shfl_xor(bm, off, 16));
    float e = act ? expf(bm - b) : 0.0f;
    float den = e;
#pragma unroll
    for (int off = 1; off < 16; off <<= 1) den += __shfl_xor(den, off, 16);
    float dk = e / den;
    float entp = 0.0f;
    if (act) {
        dist[(size_t)v * DP + k] = dk;
        entp = -dk * log2f(dk + 1e-6f);
    }
    // argmax with first-max (lowest index on tie) semantics
    float av = act ? dk : -1.0f;
    int   ai = k;
#pragma unroll
    for (int off = 1; off < 16; off <<= 1) {
        float ov = __shfl_xor(av, off, 16);
        int   oi = __shfl_xor(ai, off, 16);
        if (ov > av || (ov == av && oi < ai)) { av = ov; ai = oi; }
    }
    if (k == 0 && v < V_N) amax[v] = ai;
    // entropy: wave reduce -> LDS -> one block atomic into spread slot
#pragma unroll
    for (int off = 32; off > 0; off >>= 1) entp += __shfl_down(entp, off, 64);
    __shared__ float sE[4];
    if ((threadIdx.x & 63) == 0) sE[threadIdx.x >> 6] = entp;
    __syncthreads();
    if (threadIdx.x == 0)
        atomicAdd(&slotE[blockIdx.x & (NSLOT - 1)], sE[0] + sE[1] + sE[2] + sE[3]);
}

// One wave per factor: per_f = drv^T C dcv, cost = C[amax,amax].
__global__ __launch_bounds__(256) void k_factor_loss(
        const float* __restrict__ cost,
        const float* __restrict__ dist,
        const int*   __restrict__ amax,
        const int*   __restrict__ rv_idx,
        const int*   __restrict__ cv_idx,
        float* __restrict__ slotP,
        float* __restrict__ slotC) {
    int gtid = blockIdx.x * 256 + threadIdx.x;
    int f    = gtid >> 6;
    int lane = threadIdx.x & 63;
    float s = 0.0f, c = 0.0f;
    if (f < F_N) {
        int rv = rv_idx[f], cv = cv_idx[f];
        const float* dr = dist + (size_t)rv * DP;
        const float* dc = dist + (size_t)cv * DP;
        const float* Cf = cost + (size_t)f * TILE;
#pragma unroll
        for (int t = 0; t < 4; ++t) {
            int e = lane + t * 64;
            if (e < TILE) {
                int i = e / DD;
                int j = e - i * DD;
                s += dr[i] * Cf[e] * dc[j];
            }
        }
        if (lane == 0) c = Cf[amax[rv] * DD + amax[cv]];
    }
#pragma unroll
    for (int off = 32; off > 0; off >>= 1) s += __shfl_down(s, off, 64);
    __shared__ float sP[4], sC[4];
    int w = threadIdx.x >> 6;
    if (lane == 0) { sP[w] = s; sC[w] = c; }
    __syncthreads();
    if (threadIdx.x == 0) {
        float tp = sP[0] + sP[1] + sP[2] + sP[3];
        float tc = sC[0] + sC[1] + sC[2] + sC[3];
        int slot = blockIdx.x & (NSLOT - 1);
        atomicAdd(&slotP[slot], tp);
        atomicAdd(&slotC[slot], tc);
    }
}

__global__ void k_final(const float* __restrict__ slotP,
                        const float* __restrict__ slotC,
                        const float* __restrict__ slotE,
                        float* __restrict__ out) {
    int t = threadIdx.x;   // 256 threads
    float p = slotP[t], c = slotC[t], g = slotE[t];
#pragma unroll
    for (int off = 32; off > 0; off >>= 1) {
        p += __shfl_down(p, off, 64);
        c += __shfl_down(c, off, 64);
        g += __shfl_down(g, off, 64);
    }
    __shared__ float sp[4], sc[4], se[4];
    if ((t & 63) == 0) { sp[t >> 6] = p; sc[t >> 6] = c; se[t >> 6] = g; }
    __syncthreads();
    if (t == 0) {
        float tp = sp[0] + sp[1] + sp[2] + sp[3];
        float tc = sc[0] + sc[1] + sc[2] + sc[3];
        float te = se[0] + se[1] + se[2] + se[3];
        out[0] = tp + 0.1f * (te / (float)V_N);
        out[1] = tc;
    }
}

extern "C" void kernel_launch(void* const* d_in, const int* in_sizes, int n_in,
                              void* d_out, int out_size, void* d_ws, size_t ws_size,
                              hipStream_t stream) {
    const float* msgs = (const float*)d_in[0];   // (4*F_N, 15)
    const float* cost = (const float*)d_in[1];   // (F_N, 15, 15)
    const int* scat   = (const int*)d_in[46];    // f2v_per_v_scatter_idxes (2*F_N)
    const int* rv     = (const int*)d_in[48];    // rv_idxes (F_N)
    const int* cv     = (const int*)d_in[49];    // cv_idxes (F_N)

    float* ws    = (float*)d_ws;
    float* m     = ws + M_OFF;
    float* dist  = ws + DIST_OFF;
    int*   cnt   = (int*)(ws + CNT_OFF);
    int*   tlist = (int*)(ws + TLIST_OFF);
    int*   amax  = (int*)(ws + AMAX_OFF);
    float* slotP = ws + SLOTP_OFF;
    float* slotC = ws + SLOTC_OFF;
    float* slotE = ws + SLOTE_OFF;
    float* out   = (float*)d_out;

    k_init<<<(V_N + 255) / 256, 256, 0, stream>>>(cnt, slotP);
    k_place<<<(T_N + 255) / 256, 256, 0, stream>>>(scat, cnt, tlist);
    k_minplus<<<F_N / MPB, 256, 0, stream>>>(msgs, cost, m);
    k_gather_softmax<<<(V_N * 16 + 255) / 256, 256, 0, stream>>>(m, cnt, tlist, dist, amax, slotE);
    k_factor_loss<<<(F_N * 64 + 255) / 256, 256, 0, stream>>>(cost, dist, amax, rv, cv, slotP, slotC);
    k_final<<<1, 256, 0, stream>>>(slotP, slotC, slotE, out);
}